// Round 2
// baseline (1880.817 us; speedup 1.0000x reference)
//
#include <hip/hip_runtime.h>
#include <hip/hip_bf16.h>

#define H_IN 256
#define H    128
#define NL   3
#define BN_EPS 1e-5f

// ---------------- degree / dinv ----------------
__global__ void degree_k(const int* __restrict__ row, float* __restrict__ deg, int E) {
    int e = blockIdx.x * blockDim.x + threadIdx.x;
    if (e < E) atomicAdd(&deg[row[e]], 1.0f);
}

__global__ void dinv_k(const float* __restrict__ deg, float* __restrict__ dinv, int N) {
    int i = blockIdx.x * blockDim.x + threadIdx.x;
    if (i < N) dinv[i] = rsqrtf(deg[i] + 1.0f);  // +1 for self-loop
}

// ---------------- BN stats: per-column sum & sumsq ----------------
__global__ void stats_k(const float* __restrict__ A, float* __restrict__ stats,
                        int N, int K, int rpb) {
    int c = threadIdx.x;              // blockDim.x == K
    int r0 = blockIdx.x * rpb;
    int r1 = min(r0 + rpb, N);
    float s = 0.f, s2 = 0.f;
    for (int r = r0; r < r1; ++r) {
        float v = A[(size_t)r * K + c];
        s += v; s2 += v * v;
    }
    atomicAdd(&stats[c], s);
    atomicAdd(&stats[K + c], s2);
}

// s[c] = gamma*rsqrt(var+eps), t[c] = beta - mu*s
__global__ void sst_k(const float* __restrict__ stats, const float* __restrict__ g,
                      const float* __restrict__ b, float* __restrict__ st, int N, int K) {
    int c = threadIdx.x;              // blockDim.x == K
    float mu = stats[c] / (float)N;
    float var = stats[K + c] / (float)N - mu * mu;
    float s = g[c] * rsqrtf(var + BN_EPS);
    st[c] = s;
    st[K + c] = b[c] - mu * s;
}

// W'[k][j] = s[k]*W[k][j];  b'[j] = bias[j] + sum_k t[k]*W[k][j]
__global__ void fold_k(const float* __restrict__ W, const float* __restrict__ st,
                       const float* __restrict__ bias, float* __restrict__ Wp,
                       float* __restrict__ bp, int K) {
    int j = blockIdx.x;               // 0..H-1
    int k = threadIdx.x;              // blockDim.x == K
    float w = W[(size_t)k * H + j];
    Wp[(size_t)k * H + j] = st[k] * w;
    __shared__ float red[256];
    red[k] = st[K + k] * w;
    __syncthreads();
    for (int o = blockDim.x >> 1; o > 0; o >>= 1) {
        if (k < o) red[k] += red[k + o];
        __syncthreads();
    }
    if (k == 0) bp[j] = bias[j] + red[0];
}

// ---------------- GEMM: C[M x 128] = A[M x K] * B[K x 128] (fp32) ----------------
#define BM 64
#define BK 32
__global__ __launch_bounds__(256) void gemm_k(const float* __restrict__ A,
                                              const float* __restrict__ B,
                                              float* __restrict__ C, int M, int K) {
    __shared__ float Ast[BK][68];     // transposed A tile: [k][row], 68 keeps 16B align + pad
    __shared__ float Bs[BK][H];
    int tid = threadIdx.x;
    int tx = tid & 31;                // col group (4 cols)
    int ty = tid >> 5;                // row group (8 rows)
    int m0 = blockIdx.x * BM;

    float acc[8][4];
#pragma unroll
    for (int i = 0; i < 8; ++i)
#pragma unroll
        for (int j = 0; j < 4; ++j) acc[i][j] = 0.f;

    int lr = tid >> 2;                // 0..63: tile row
    int lk = (tid & 3) * 8;           // 0,8,16,24: k offset

    for (int kb = 0; kb < K; kb += BK) {
        __syncthreads();
        // A tile -> LDS (transposed)
        {
            float av[8];
            int grow = m0 + lr;
            if (grow < M) {
                const float4* p = (const float4*)(A + (size_t)grow * K + kb + lk);
                float4 f0 = p[0], f1 = p[1];
                av[0]=f0.x; av[1]=f0.y; av[2]=f0.z; av[3]=f0.w;
                av[4]=f1.x; av[5]=f1.y; av[6]=f1.z; av[7]=f1.w;
            } else {
#pragma unroll
                for (int j = 0; j < 8; ++j) av[j] = 0.f;
            }
#pragma unroll
            for (int j = 0; j < 8; ++j) Ast[lk + j][lr] = av[j];
        }
        // B tile -> LDS (contiguous BK*H floats)
        {
            const float4* src = (const float4*)(B + (size_t)kb * H);
            float4* dst = (float4*)&Bs[0][0];
#pragma unroll
            for (int q = 0; q < 4; ++q) {
                int idx = tid + q * 256;
                dst[idx] = src[idx];
            }
        }
        __syncthreads();
#pragma unroll
        for (int k = 0; k < BK; ++k) {
            float4 a0 = *(const float4*)&Ast[k][ty * 8];
            float4 a1 = *(const float4*)&Ast[k][ty * 8 + 4];
            float4 b0 = *(const float4*)&Bs[k][tx * 4];
            float a[8] = {a0.x, a0.y, a0.z, a0.w, a1.x, a1.y, a1.z, a1.w};
            float bb[4] = {b0.x, b0.y, b0.z, b0.w};
#pragma unroll
            for (int i = 0; i < 8; ++i)
#pragma unroll
                for (int j = 0; j < 4; ++j)
                    acc[i][j] = fmaf(a[i], bb[j], acc[i][j]);
        }
    }
#pragma unroll
    for (int i = 0; i < 8; ++i) {
        int grow = m0 + ty * 8 + i;
        if (grow < M) {
            float4 v = make_float4(acc[i][0], acc[i][1], acc[i][2], acc[i][3]);
            *(float4*)(C + (size_t)grow * H + tx * 4) = v;
        }
    }
}

// ---------------- aggregation ----------------
// init: O[i][f] = dinv[i]^2 * Y[i][f] + b'[f]   (self-loop + bias)
__global__ void aggin_k(const float* __restrict__ Y, const float* __restrict__ dinv,
                        const float* __restrict__ bp, float* __restrict__ O, int total) {
    int idx = blockIdx.x * blockDim.x + threadIdx.x;
    if (idx < total) {
        int i = idx >> 7;
        int f = idx & 127;
        float d = dinv[i];
        O[idx] = d * d * Y[idx] + bp[f];
    }
}

// edges: O[col][f] += dinv[row]*dinv[col] * Y[row][f]
__global__ __launch_bounds__(256) void edge_k(const int* __restrict__ row,
                                              const int* __restrict__ col,
                                              const float* __restrict__ dinv,
                                              const float* __restrict__ Y,
                                              float* __restrict__ O, int total) {
    int idx = blockIdx.x * blockDim.x + threadIdx.x;
    if (idx < total) {
        int e = idx >> 7;
        int f = idx & 127;
        int r = row[e], c = col[e];
        float nv = dinv[r] * dinv[c];
        atomicAdd(&O[(size_t)c * H + f], nv * Y[(size_t)r * H + f]);
    }
}

// ---------------- host ----------------
static void run_layer(const float* A, int K,
                      const float* W, const float* bias, const float* g, const float* bb,
                      int N, int E, const int* row, const int* col,
                      float* stats, float* st, float* Wp, float* bp,
                      float* dinv, float* Y, float* O, hipStream_t stream) {
    hipMemsetAsync(stats, 0, 2 * K * sizeof(float), stream);
    int sb = (N + 127) / 128;
    stats_k<<<sb, K, 0, stream>>>(A, stats, N, K, 128);
    sst_k<<<1, K, 0, stream>>>(stats, g, bb, st, N, K);
    fold_k<<<H, K, 0, stream>>>(W, st, bias, Wp, bp, K);
    int gb = (N + BM - 1) / BM;
    gemm_k<<<gb, 256, 0, stream>>>(A, Wp, Y, N, K);
    int tot = N * H;
    aggin_k<<<(tot + 255) / 256, 256, 0, stream>>>(Y, dinv, bp, O, tot);
    int etot = E * H;
    edge_k<<<(etot + 255) / 256, 256, 0, stream>>>(row, col, dinv, Y, O, etot);
}

extern "C" void kernel_launch(void* const* d_in, const int* in_sizes, int n_in,
                              void* d_out, int out_size, void* d_ws, size_t ws_size,
                              hipStream_t stream) {
    const float* x     = (const float*)d_in[0];
    const int*   ei    = (const int*)d_in[1];
    const float* bnfg  = (const float*)d_in[2];
    const float* bnfb  = (const float*)d_in[3];
    const float* Wfeat = (const float*)d_in[4];
    const float* bfeat = (const float*)d_in[5];
    const float* bng   = (const float*)d_in[6];
    const float* bnb   = (const float*)d_in[7];
    const float* Ws    = (const float*)d_in[8];
    const float* bs    = (const float*)d_in[9];

    int N = in_sizes[0] / H_IN;      // 50000
    int E = in_sizes[1] / 2;         // 800000
    const int* row = ei;
    const int* col = ei + E;

    float* w = (float*)d_ws;
    float* deg   = w;  w += N;
    float* dinv  = w;  w += N;
    float* stats = w;  w += 512;
    float* st    = w;  w += 512;
    float* Wp    = w;  w += H_IN * H;
    float* bp    = w;  w += H;
    float* Y     = w;  w += (size_t)N * H;
    float* ACT   = w;

    float* out = (float*)d_out;

    hipMemsetAsync(deg, 0, N * sizeof(float), stream);
    degree_k<<<(E + 255) / 256, 256, 0, stream>>>(row, deg, E);
    dinv_k<<<(N + 255) / 256, 256, 0, stream>>>(deg, dinv, N);

    // layer 0: BN(256) folded into GEMM 256->128, aggregate -> ACT
    run_layer(x, H_IN, Wfeat, bfeat, bnfg, bnfb,
              N, E, row, col, stats, st, Wp, bp, dinv, Y, ACT, stream);

    // layers 1..3: BN(128) folded into GEMM 128->128; last layer writes d_out
    for (int l = 0; l < NL; ++l) {
        float* O = (l == NL - 1) ? out : ACT;
        run_layer(ACT, H,
                  Ws + (size_t)l * H * H, bs + (size_t)l * H,
                  bng + (size_t)l * H, bnb + (size_t)l * H,
                  N, E, row, col, stats, st, Wp, bp, dinv, Y, O, stream);
    }
}

// Round 3
// 870.179 us; speedup vs baseline: 2.1614x; 2.1614x over previous
//
#include <hip/hip_runtime.h>
#include <hip/hip_bf16.h>

#define H_IN 256
#define H    128
#define NL   3
#define BN_EPS 1e-5f

// ---------------- degree / dinv ----------------
__global__ void degree_k(const int* __restrict__ row, float* __restrict__ deg, int E) {
    int e = blockIdx.x * blockDim.x + threadIdx.x;
    if (e < E) atomicAdd(&deg[row[e]], 1.0f);
}

__global__ void dinv_k(const float* __restrict__ deg, float* __restrict__ dinv, int N) {
    int i = blockIdx.x * blockDim.x + threadIdx.x;
    if (i < N) dinv[i] = rsqrtf(deg[i] + 1.0f);  // +1 for self-loop
}

// ---------------- CSR build (sorted by destination col) ----------------
__global__ void hist_k(const int* __restrict__ col, int* __restrict__ cnt, int E) {
    int e = blockIdx.x * blockDim.x + threadIdx.x;
    if (e < E) atomicAdd(&cnt[col[e]], 1);
}

// per-block inclusive scan -> exclusive within block; block totals to bsum
__global__ void scan1_k(const int* __restrict__ cnt, int* __restrict__ rowptr,
                        int* __restrict__ bsum, int N) {
    __shared__ int sh[256];
    int tid = threadIdx.x;
    int i = blockIdx.x * 256 + tid;
    int v = (i < N) ? cnt[i] : 0;
    sh[tid] = v;
    __syncthreads();
    for (int o = 1; o < 256; o <<= 1) {
        int t = (tid >= o) ? sh[tid - o] : 0;
        __syncthreads();
        sh[tid] += t;
        __syncthreads();
    }
    if (i < N) rowptr[i] = sh[tid] - v;          // exclusive within block
    if (tid == 255) bsum[blockIdx.x] = sh[255];  // block total
}

// single-block exclusive scan of block sums (nb <= 256)
__global__ void scan2_k(int* __restrict__ bsum, int nb) {
    __shared__ int sh[256];
    int tid = threadIdx.x;
    int v = (tid < nb) ? bsum[tid] : 0;
    sh[tid] = v;
    __syncthreads();
    for (int o = 1; o < 256; o <<= 1) {
        int t = (tid >= o) ? sh[tid - o] : 0;
        __syncthreads();
        sh[tid] += t;
        __syncthreads();
    }
    if (tid < nb) bsum[tid] = sh[tid] - v;       // exclusive offset
}

__global__ void scan3_k(int* __restrict__ rowptr, const int* __restrict__ bsum,
                        int N, int E) {
    int i = blockIdx.x * 256 + threadIdx.x;
    if (i < N) rowptr[i] += bsum[blockIdx.x];
    if (i == 0) rowptr[N] = E;
}

__global__ void scat_k(const int* __restrict__ row, const int* __restrict__ col,
                       const float* __restrict__ dinv, const int* __restrict__ rowptr,
                       int* __restrict__ cursor, int* __restrict__ esrc,
                       float* __restrict__ enorm, int E) {
    int e = blockIdx.x * blockDim.x + threadIdx.x;
    if (e < E) {
        int c = col[e], r = row[e];
        int p = rowptr[c] + atomicAdd(&cursor[c], 1);
        esrc[p]  = r;
        enorm[p] = dinv[r] * dinv[c];
    }
}

// ---------------- BN stats: per-column sum & sumsq ----------------
__global__ void stats_k(const float* __restrict__ A, float* __restrict__ stats,
                        int N, int K, int rpb) {
    int c = threadIdx.x;              // blockDim.x == K
    int r0 = blockIdx.x * rpb;
    int r1 = min(r0 + rpb, N);
    float s = 0.f, s2 = 0.f;
    for (int r = r0; r < r1; ++r) {
        float v = A[(size_t)r * K + c];
        s += v; s2 += v * v;
    }
    atomicAdd(&stats[c], s);
    atomicAdd(&stats[K + c], s2);
}

// s[c] = gamma*rsqrt(var+eps), t[c] = beta - mu*s
__global__ void sst_k(const float* __restrict__ stats, const float* __restrict__ g,
                      const float* __restrict__ b, float* __restrict__ st, int N, int K) {
    int c = threadIdx.x;              // blockDim.x == K
    float mu = stats[c] / (float)N;
    float var = stats[K + c] / (float)N - mu * mu;
    float s = g[c] * rsqrtf(var + BN_EPS);
    st[c] = s;
    st[K + c] = b[c] - mu * s;
}

// W'[k][j] = s[k]*W[k][j];  b'[j] = bias[j] + sum_k t[k]*W[k][j]
__global__ void fold_k(const float* __restrict__ W, const float* __restrict__ st,
                       const float* __restrict__ bias, float* __restrict__ Wp,
                       float* __restrict__ bp, int K) {
    int j = blockIdx.x;               // 0..H-1
    int k = threadIdx.x;              // blockDim.x == K
    float w = W[(size_t)k * H + j];
    Wp[(size_t)k * H + j] = st[k] * w;
    __shared__ float red[256];
    red[k] = st[K + k] * w;
    __syncthreads();
    for (int o = blockDim.x >> 1; o > 0; o >>= 1) {
        if (k < o) red[k] += red[k + o];
        __syncthreads();
    }
    if (k == 0) bp[j] = bias[j] + red[0];
}

// ---------------- GEMM: C[M x 128] = A[M x K] * B[K x 128] (fp32) ----------------
#define BM 64
#define BK 32
__global__ __launch_bounds__(256) void gemm_k(const float* __restrict__ A,
                                              const float* __restrict__ B,
                                              float* __restrict__ C, int M, int K) {
    __shared__ float Ast[BK][68];
    __shared__ float Bs[BK][H];
    int tid = threadIdx.x;
    int tx = tid & 31;
    int ty = tid >> 5;
    int m0 = blockIdx.x * BM;

    float acc[8][4];
#pragma unroll
    for (int i = 0; i < 8; ++i)
#pragma unroll
        for (int j = 0; j < 4; ++j) acc[i][j] = 0.f;

    int lr = tid >> 2;
    int lk = (tid & 3) * 8;

    for (int kb = 0; kb < K; kb += BK) {
        __syncthreads();
        {
            float av[8];
            int grow = m0 + lr;
            if (grow < M) {
                const float4* p = (const float4*)(A + (size_t)grow * K + kb + lk);
                float4 f0 = p[0], f1 = p[1];
                av[0]=f0.x; av[1]=f0.y; av[2]=f0.z; av[3]=f0.w;
                av[4]=f1.x; av[5]=f1.y; av[6]=f1.z; av[7]=f1.w;
            } else {
#pragma unroll
                for (int j = 0; j < 8; ++j) av[j] = 0.f;
            }
#pragma unroll
            for (int j = 0; j < 8; ++j) Ast[lk + j][lr] = av[j];
        }
        {
            const float4* src = (const float4*)(B + (size_t)kb * H);
            float4* dst = (float4*)&Bs[0][0];
#pragma unroll
            for (int q = 0; q < 4; ++q) {
                int idx = tid + q * 256;
                dst[idx] = src[idx];
            }
        }
        __syncthreads();
#pragma unroll
        for (int k = 0; k < BK; ++k) {
            float4 a0 = *(const float4*)&Ast[k][ty * 8];
            float4 a1 = *(const float4*)&Ast[k][ty * 8 + 4];
            float4 b0 = *(const float4*)&Bs[k][tx * 4];
            float a[8] = {a0.x, a0.y, a0.z, a0.w, a1.x, a1.y, a1.z, a1.w};
            float bb[4] = {b0.x, b0.y, b0.z, b0.w};
#pragma unroll
            for (int i = 0; i < 8; ++i)
#pragma unroll
                for (int j = 0; j < 4; ++j)
                    acc[i][j] = fmaf(a[i], bb[j], acc[i][j]);
        }
    }
#pragma unroll
    for (int i = 0; i < 8; ++i) {
        int grow = m0 + ty * 8 + i;
        if (grow < M) {
            float4 v = make_float4(acc[i][0], acc[i][1], acc[i][2], acc[i][3]);
            *(float4*)(C + (size_t)grow * H + tx * 4) = v;
        }
    }
}

// ---------------- CSR aggregation ----------------
// 32 lanes per node (float4 each), 8 nodes per 256-thread block.
// O[i] = dinv[i]^2*Y[i] + bp + sum_{p in [rowptr[i],rowptr[i+1])} enorm[p]*Y[esrc[p]]
__global__ __launch_bounds__(256) void csragg_k(const int* __restrict__ rowptr,
                                                const int* __restrict__ esrc,
                                                const float* __restrict__ enorm,
                                                const float* __restrict__ Y,
                                                const float* __restrict__ dinv,
                                                const float* __restrict__ bp,
                                                float* __restrict__ O, int N) {
    int node = blockIdx.x * 8 + (threadIdx.x >> 5);
    int fq = threadIdx.x & 31;                // float4 lane within row
    if (node >= N) return;
    const float4* Y4 = (const float4*)Y;
    float4 y = Y4[(size_t)node * 32 + fq];
    float d = dinv[node];
    float dd = d * d;
    float4 acc = ((const float4*)bp)[fq];
    acc.x += dd * y.x; acc.y += dd * y.y; acc.z += dd * y.z; acc.w += dd * y.w;
    int s = rowptr[node], e = rowptr[node + 1];
    for (int p = s; p < e; ++p) {
        int src = esrc[p];
        float nv = enorm[p];
        float4 v = Y4[(size_t)src * 32 + fq];
        acc.x += nv * v.x; acc.y += nv * v.y; acc.z += nv * v.z; acc.w += nv * v.w;
    }
    ((float4*)O)[(size_t)node * 32 + fq] = acc;
}

// ---------------- host ----------------
static void run_layer(const float* A, int K,
                      const float* W, const float* bias, const float* g, const float* bb,
                      int N, const int* rowptr, const int* esrc, const float* enorm,
                      float* stats, float* st, float* Wp, float* bp,
                      float* dinv, float* Y, float* O, hipStream_t stream) {
    hipMemsetAsync(stats, 0, 2 * K * sizeof(float), stream);
    int sb = (N + 127) / 128;
    stats_k<<<sb, K, 0, stream>>>(A, stats, N, K, 128);
    sst_k<<<1, K, 0, stream>>>(stats, g, bb, st, N, K);
    fold_k<<<H, K, 0, stream>>>(W, st, bias, Wp, bp, K);
    int gb = (N + BM - 1) / BM;
    gemm_k<<<gb, 256, 0, stream>>>(A, Wp, Y, N, K);
    csragg_k<<<(N + 7) / 8, 256, 0, stream>>>(rowptr, esrc, enorm, Y, dinv, bp, O, N);
}

extern "C" void kernel_launch(void* const* d_in, const int* in_sizes, int n_in,
                              void* d_out, int out_size, void* d_ws, size_t ws_size,
                              hipStream_t stream) {
    const float* x     = (const float*)d_in[0];
    const int*   ei    = (const int*)d_in[1];
    const float* bnfg  = (const float*)d_in[2];
    const float* bnfb  = (const float*)d_in[3];
    const float* Wfeat = (const float*)d_in[4];
    const float* bfeat = (const float*)d_in[5];
    const float* bng   = (const float*)d_in[6];
    const float* bnb   = (const float*)d_in[7];
    const float* Ws    = (const float*)d_in[8];
    const float* bs    = (const float*)d_in[9];

    int N = in_sizes[0] / H_IN;      // 50000
    int E = in_sizes[1] / 2;         // 800000
    const int* row = ei;
    const int* col = ei + E;

    float* w = (float*)d_ws;
    float* deg    = w;  w += N;       // reused as cnt, then cursor (int)
    float* dinv   = w;  w += N;
    float* stats  = w;  w += 512;
    float* st     = w;  w += 512;
    float* Wp     = w;  w += H_IN * H;
    float* bp     = w;  w += H;
    int*   rowptr = (int*)w;  w += N + 4;
    int*   bsum   = (int*)w;  w += 256;
    int*   esrc   = (int*)w;  w += E;
    float* enorm  = w;  w += E;
    float* Y      = w;  w += (size_t)N * H;
    float* ACT    = w;

    float* out = (float*)d_out;

    // degrees (row-based, same as reference since symmetric norm uses deg over row)
    hipMemsetAsync(deg, 0, N * sizeof(float), stream);
    degree_k<<<(E + 255) / 256, 256, 0, stream>>>(row, deg, E);
    dinv_k<<<(N + 255) / 256, 256, 0, stream>>>(deg, dinv, N);

    // CSR by destination
    int* cnt = (int*)deg;
    hipMemsetAsync(cnt, 0, N * sizeof(int), stream);
    hist_k<<<(E + 255) / 256, 256, 0, stream>>>(col, cnt, E);
    int nb = (N + 255) / 256;
    scan1_k<<<nb, 256, 0, stream>>>(cnt, rowptr, bsum, N);
    scan2_k<<<1, 256, 0, stream>>>(bsum, nb);
    scan3_k<<<nb, 256, 0, stream>>>(rowptr, bsum, N, E);
    int* cursor = (int*)deg;
    hipMemsetAsync(cursor, 0, N * sizeof(int), stream);
    scat_k<<<(E + 255) / 256, 256, 0, stream>>>(row, col, dinv, rowptr, cursor, esrc, enorm, E);

    // layer 0: BN(256) folded into GEMM 256->128, aggregate -> ACT
    run_layer(x, H_IN, Wfeat, bfeat, bnfg, bnfb,
              N, rowptr, esrc, enorm, stats, st, Wp, bp, dinv, Y, ACT, stream);

    // layers 1..3: BN(128) folded into GEMM 128->128; last layer writes d_out
    for (int l = 0; l < NL; ++l) {
        float* O = (l == NL - 1) ? out : ACT;
        run_layer(ACT, H,
                  Ws + (size_t)l * H * H, bs + (size_t)l * H,
                  bng + (size_t)l * H, bnb + (size_t)l * H,
                  N, rowptr, esrc, enorm, stats, st, Wp, bp, dinv, Y, O, stream);
    }
}

// Round 4
// 730.756 us; speedup vs baseline: 2.5738x; 1.1908x over previous
//
#include <hip/hip_runtime.h>
#include <hip/hip_bf16.h>

#define H_IN 256
#define H    128
#define NL   3
#define BN_EPS 1e-5f

using u16 = unsigned short;
typedef __attribute__((ext_vector_type(8))) unsigned short us8;

__device__ __forceinline__ float b2f(u16 u) {
    return __uint_as_float(((unsigned int)u) << 16);
}
__device__ __forceinline__ u16 f2b(float f) {  // round-to-nearest-even
    unsigned int u = __float_as_uint(f);
    u += 0x7FFF + ((u >> 16) & 1);
    return (u16)(u >> 16);
}

// ---------------- degree / dinv ----------------
__global__ void degree_k(const int* __restrict__ row, float* __restrict__ deg, int E) {
    int e = blockIdx.x * blockDim.x + threadIdx.x;
    if (e < E) atomicAdd(&deg[row[e]], 1.0f);
}

__global__ void dinv_k(const float* __restrict__ deg, float* __restrict__ dinv, int N) {
    int i = blockIdx.x * blockDim.x + threadIdx.x;
    if (i < N) dinv[i] = rsqrtf(deg[i] + 1.0f);  // +1 for self-loop
}

// ---------------- CSR build (sorted by destination col) ----------------
__global__ void hist_k(const int* __restrict__ col, int* __restrict__ cnt, int E) {
    int e = blockIdx.x * blockDim.x + threadIdx.x;
    if (e < E) atomicAdd(&cnt[col[e]], 1);
}

__global__ void scan1_k(const int* __restrict__ cnt, int* __restrict__ rowptr,
                        int* __restrict__ bsum, int N) {
    __shared__ int sh[256];
    int tid = threadIdx.x;
    int i = blockIdx.x * 256 + tid;
    int v = (i < N) ? cnt[i] : 0;
    sh[tid] = v;
    __syncthreads();
    for (int o = 1; o < 256; o <<= 1) {
        int t = (tid >= o) ? sh[tid - o] : 0;
        __syncthreads();
        sh[tid] += t;
        __syncthreads();
    }
    if (i < N) rowptr[i] = sh[tid] - v;
    if (tid == 255) bsum[blockIdx.x] = sh[255];
}

__global__ void scan2_k(int* __restrict__ bsum, int nb) {
    __shared__ int sh[256];
    int tid = threadIdx.x;
    int v = (tid < nb) ? bsum[tid] : 0;
    sh[tid] = v;
    __syncthreads();
    for (int o = 1; o < 256; o <<= 1) {
        int t = (tid >= o) ? sh[tid - o] : 0;
        __syncthreads();
        sh[tid] += t;
        __syncthreads();
    }
    if (tid < nb) bsum[tid] = sh[tid] - v;
}

__global__ void scan3_k(int* __restrict__ rowptr, const int* __restrict__ bsum,
                        int N, int E) {
    int i = blockIdx.x * 256 + threadIdx.x;
    if (i < N) rowptr[i] += bsum[blockIdx.x];
    if (i == 0) rowptr[N] = E;
}

__global__ void scat_k(const int* __restrict__ row, const int* __restrict__ col,
                       const float* __restrict__ dinv, const int* __restrict__ rowptr,
                       int* __restrict__ cursor, int* __restrict__ esrc,
                       float* __restrict__ enorm, int E) {
    int e = blockIdx.x * blockDim.x + threadIdx.x;
    if (e < E) {
        int c = col[e], r = row[e];
        int p = rowptr[c] + atomicAdd(&cursor[c], 1);
        esrc[p]  = r;
        enorm[p] = dinv[r] * dinv[c];
    }
}

// ---------------- BN stats: per-column sum & sumsq ----------------
__global__ void stats_k(const float* __restrict__ A, float* __restrict__ stats,
                        int N, int K, int rpb) {
    int c = threadIdx.x;              // blockDim.x == K
    int r0 = blockIdx.x * rpb;
    int r1 = min(r0 + rpb, N);
    float s = 0.f, s2 = 0.f;
    for (int r = r0; r < r1; ++r) {
        float v = A[(size_t)r * K + c];
        s += v; s2 += v * v;
    }
    atomicAdd(&stats[c], s);
    atomicAdd(&stats[K + c], s2);
}

// fused: compute s/t from stats inline, then W'[k][j]=s[k]W[k][j], b'[j]=bias[j]+sum_k t[k]W[k][j]
__global__ void fold_k(const float* __restrict__ W, const float* __restrict__ stats,
                       const float* __restrict__ g, const float* __restrict__ b,
                       const float* __restrict__ bias, float* __restrict__ Wp,
                       float* __restrict__ bp, int N, int K) {
    int j = blockIdx.x;               // 0..H-1
    int k = threadIdx.x;              // blockDim.x == K
    float mu = stats[k] / (float)N;
    float var = stats[K + k] / (float)N - mu * mu;
    float s = g[k] * rsqrtf(var + BN_EPS);
    float t = b[k] - mu * s;
    float w = W[(size_t)k * H + j];
    Wp[(size_t)k * H + j] = s * w;
    __shared__ float red[256];
    red[k] = t * w;
    __syncthreads();
    for (int o = blockDim.x >> 1; o > 0; o >>= 1) {
        if (k < o) red[k] += red[k + o];
        __syncthreads();
    }
    if (k == 0) bp[j] = bias[j] + red[0];
}

// ---------------- GEMM: Yb[M x 128] (bf16) = A[M x K] * B[K x 128] ----------------
#define BM 64
#define BK 32
__global__ __launch_bounds__(256) void gemm_k(const float* __restrict__ A,
                                              const float* __restrict__ B,
                                              u16* __restrict__ Yb, int M, int K) {
    __shared__ float Ast[BK][68];
    __shared__ float Bs[BK][H];
    int tid = threadIdx.x;
    int tx = tid & 31;
    int ty = tid >> 5;
    int m0 = blockIdx.x * BM;

    float acc[8][4];
#pragma unroll
    for (int i = 0; i < 8; ++i)
#pragma unroll
        for (int j = 0; j < 4; ++j) acc[i][j] = 0.f;

    int lr = tid >> 2;
    int lk = (tid & 3) * 8;

    for (int kb = 0; kb < K; kb += BK) {
        __syncthreads();
        {
            float av[8];
            int grow = m0 + lr;
            if (grow < M) {
                const float4* p = (const float4*)(A + (size_t)grow * K + kb + lk);
                float4 f0 = p[0], f1 = p[1];
                av[0]=f0.x; av[1]=f0.y; av[2]=f0.z; av[3]=f0.w;
                av[4]=f1.x; av[5]=f1.y; av[6]=f1.z; av[7]=f1.w;
            } else {
#pragma unroll
                for (int j = 0; j < 8; ++j) av[j] = 0.f;
            }
#pragma unroll
            for (int j = 0; j < 8; ++j) Ast[lk + j][lr] = av[j];
        }
        {
            const float4* src = (const float4*)(B + (size_t)kb * H);
            float4* dst = (float4*)&Bs[0][0];
#pragma unroll
            for (int q = 0; q < 4; ++q) {
                int idx = tid + q * 256;
                dst[idx] = src[idx];
            }
        }
        __syncthreads();
#pragma unroll
        for (int k = 0; k < BK; ++k) {
            float4 a0 = *(const float4*)&Ast[k][ty * 8];
            float4 a1 = *(const float4*)&Ast[k][ty * 8 + 4];
            float4 b0 = *(const float4*)&Bs[k][tx * 4];
            float a[8] = {a0.x, a0.y, a0.z, a0.w, a1.x, a1.y, a1.z, a1.w};
            float bb[4] = {b0.x, b0.y, b0.z, b0.w};
#pragma unroll
            for (int i = 0; i < 8; ++i)
#pragma unroll
                for (int j = 0; j < 4; ++j)
                    acc[i][j] = fmaf(a[i], bb[j], acc[i][j]);
        }
    }
#pragma unroll
    for (int i = 0; i < 8; ++i) {
        int grow = m0 + ty * 8 + i;
        if (grow < M) {
            ushort4 v;
            v.x = f2b(acc[i][0]); v.y = f2b(acc[i][1]);
            v.z = f2b(acc[i][2]); v.w = f2b(acc[i][3]);
            *(ushort4*)(Yb + (size_t)grow * H + tx * 4) = v;
        }
    }
}

// ---------------- CSR aggregation (bf16 gather) ----------------
// 16 lanes per node (ushort8 = 16B each), 16 nodes per 256-thread block.
// O[i] = dinv[i]^2*Y[i] + bp + sum_p enorm[p]*Y[esrc[p]]
__global__ __launch_bounds__(256) void csragg_k(const int* __restrict__ rowptr,
                                                const int* __restrict__ esrc,
                                                const float* __restrict__ enorm,
                                                const u16* __restrict__ Yb,
                                                const float* __restrict__ dinv,
                                                const float* __restrict__ bp,
                                                float* __restrict__ O, int N) {
    int node = blockIdx.x * 16 + (threadIdx.x >> 4);
    int fl = threadIdx.x & 15;               // 8-feature group
    if (node >= N) return;
    const us8* Y8 = (const us8*)Yb;          // row = 16 us8
    float acc[8];
    {
        us8 ys = Y8[(size_t)node * 16 + fl];
        float d = dinv[node];
        float dd = d * d;
        float4 b0 = ((const float4*)bp)[fl * 2];
        float4 b1 = ((const float4*)bp)[fl * 2 + 1];
        acc[0] = b0.x + dd * b2f(ys[0]); acc[1] = b0.y + dd * b2f(ys[1]);
        acc[2] = b0.z + dd * b2f(ys[2]); acc[3] = b0.w + dd * b2f(ys[3]);
        acc[4] = b1.x + dd * b2f(ys[4]); acc[5] = b1.y + dd * b2f(ys[5]);
        acc[6] = b1.z + dd * b2f(ys[6]); acc[7] = b1.w + dd * b2f(ys[7]);
    }
    int s = rowptr[node], e = rowptr[node + 1];
    int p = s;
    for (; p + 1 < e; p += 2) {
        int s0 = esrc[p], s1 = esrc[p + 1];
        float n0 = enorm[p], n1 = enorm[p + 1];
        us8 v0 = Y8[(size_t)s0 * 16 + fl];
        us8 v1 = Y8[(size_t)s1 * 16 + fl];
#pragma unroll
        for (int j = 0; j < 8; ++j) acc[j] += n0 * b2f(v0[j]);
#pragma unroll
        for (int j = 0; j < 8; ++j) acc[j] += n1 * b2f(v1[j]);
    }
    if (p < e) {
        int s0 = esrc[p];
        float n0 = enorm[p];
        us8 v0 = Y8[(size_t)s0 * 16 + fl];
#pragma unroll
        for (int j = 0; j < 8; ++j) acc[j] += n0 * b2f(v0[j]);
    }
    float4* O4 = (float4*)O;
    O4[(size_t)node * 32 + fl * 2]     = make_float4(acc[0], acc[1], acc[2], acc[3]);
    O4[(size_t)node * 32 + fl * 2 + 1] = make_float4(acc[4], acc[5], acc[6], acc[7]);
}

// ---------------- host ----------------
static void run_layer(const float* A, int K,
                      const float* W, const float* bias, const float* g, const float* bb,
                      int N, const int* rowptr, const int* esrc, const float* enorm,
                      float* stats, float* Wp, float* bp,
                      float* dinv, u16* Yb, float* O, hipStream_t stream) {
    hipMemsetAsync(stats, 0, 2 * K * sizeof(float), stream);
    int sb = (N + 127) / 128;
    stats_k<<<sb, K, 0, stream>>>(A, stats, N, K, 128);
    fold_k<<<H, K, 0, stream>>>(W, stats, g, bb, bias, Wp, bp, N, K);
    int gb = (N + BM - 1) / BM;
    gemm_k<<<gb, 256, 0, stream>>>(A, Wp, Yb, N, K);
    csragg_k<<<(N + 15) / 16, 256, 0, stream>>>(rowptr, esrc, enorm, Yb, dinv, bp, O, N);
}

extern "C" void kernel_launch(void* const* d_in, const int* in_sizes, int n_in,
                              void* d_out, int out_size, void* d_ws, size_t ws_size,
                              hipStream_t stream) {
    const float* x     = (const float*)d_in[0];
    const int*   ei    = (const int*)d_in[1];
    const float* bnfg  = (const float*)d_in[2];
    const float* bnfb  = (const float*)d_in[3];
    const float* Wfeat = (const float*)d_in[4];
    const float* bfeat = (const float*)d_in[5];
    const float* bng   = (const float*)d_in[6];
    const float* bnb   = (const float*)d_in[7];
    const float* Ws    = (const float*)d_in[8];
    const float* bs    = (const float*)d_in[9];

    int N = in_sizes[0] / H_IN;      // 50000
    int E = in_sizes[1] / 2;         // 800000
    const int* row = ei;
    const int* col = ei + E;

    float* w = (float*)d_ws;
    float* deg    = w;  w += N;       // reused as cnt, then cursor (int)
    float* dinv   = w;  w += N;
    float* stats  = w;  w += 512;
    float* Wp     = w;  w += H_IN * H;
    float* bp     = w;  w += H;
    int*   rowptr = (int*)w;  w += N + 4;
    int*   bsum   = (int*)w;  w += 256;
    int*   esrc   = (int*)w;  w += E;
    float* enorm  = w;  w += E;
    u16*   Yb     = (u16*)w;  w += (size_t)N * H / 2;   // bf16 Y
    float* ACT    = w;

    float* out = (float*)d_out;

    hipMemsetAsync(deg, 0, N * sizeof(float), stream);
    degree_k<<<(E + 255) / 256, 256, 0, stream>>>(row, deg, E);
    dinv_k<<<(N + 255) / 256, 256, 0, stream>>>(deg, dinv, N);

    // CSR by destination
    int* cnt = (int*)deg;
    hipMemsetAsync(cnt, 0, N * sizeof(int), stream);
    hist_k<<<(E + 255) / 256, 256, 0, stream>>>(col, cnt, E);
    int nb = (N + 255) / 256;
    scan1_k<<<nb, 256, 0, stream>>>(cnt, rowptr, bsum, N);
    scan2_k<<<1, 256, 0, stream>>>(bsum, nb);
    scan3_k<<<nb, 256, 0, stream>>>(rowptr, bsum, N, E);
    int* cursor = (int*)deg;
    hipMemsetAsync(cursor, 0, N * sizeof(int), stream);
    scat_k<<<(E + 255) / 256, 256, 0, stream>>>(row, col, dinv, rowptr, cursor, esrc, enorm, E);

    // layer 0: BN(256) folded into GEMM 256->128, aggregate -> ACT
    run_layer(x, H_IN, Wfeat, bfeat, bnfg, bnfb,
              N, rowptr, esrc, enorm, stats, Wp, bp, dinv, Yb, ACT, stream);

    // layers 1..3: BN(128) folded into GEMM 128->128; last layer writes d_out
    for (int l = 0; l < NL; ++l) {
        float* O = (l == NL - 1) ? out : ACT;
        run_layer(ACT, H,
                  Ws + (size_t)l * H * H, bs + (size_t)l * H,
                  bng + (size_t)l * H, bnb + (size_t)l * H,
                  N, rowptr, esrc, enorm, stats, Wp, bp, dinv, Yb, O, stream);
    }
}